// Round 1
// baseline (311.466 us; speedup 1.0000x reference)
//
#include <hip/hip_runtime.h>
#include <stdint.h>
#include <stddef.h>

typedef __bf16 bf16;
typedef bf16 bf16x4 __attribute__((ext_vector_type(4)));
typedef bf16 bf16x8 __attribute__((ext_vector_type(8)));
typedef float f32x4 __attribute__((ext_vector_type(4)));
typedef float f32x16 __attribute__((ext_vector_type(16)));

#define T_DIM 365
#define K1    368     // padded K for layer 1
#define SX    376     // LDS stride (bf16 elems) for Xb: 752B = 47*16 (odd multiple of 16B)
#define N1    512
#define SH1   520     // 1040B = 65*16
#define N2    256
#define K2    512
#define SH2   264     // 528B = 33*16
#define N3    128
#define K3    256
#define SCB   184     // 368B = 23*16 (combined buffer: 128 seq + 32 stat)
#define KC1   160
#define SC1   72      // 144B = 9*16
#define KC2   64
#define SC2   33      // f32 stride (odd dwords-ish; fine)

// ws element offsets (bf16 elements)
#define WT1_OFF  0        // [512][368]
#define WT2_OFF  188416   // [256][512]
#define WT3_OFF  319488   // [128][256]
#define WTC1_OFF 352256   // [64][160]
#define WTC2_OFF 362496   // [32][64]
#define WTOTAL   364544

__global__ void prep_weights(const float* __restrict__ W1, const float* __restrict__ W2,
                             const float* __restrict__ W3, const float* __restrict__ Wc1,
                             const float* __restrict__ Wc2, bf16* __restrict__ ws) {
    int idx = blockIdx.x * 256 + threadIdx.x;
    if (idx < 188416) {                       // Wt1[n][k] from W1[365][512]
        int n = idx / K1, k = idx % K1;
        ws[WT1_OFF + idx] = (k < T_DIM) ? (bf16)W1[k * 512 + n] : (bf16)0.0f;
        return;
    }
    idx -= 188416;
    if (idx < 131072) {                       // Wt2[n][k] from W2[512][256]
        int n = idx / K2, k = idx % K2;
        ws[WT2_OFF + idx] = (bf16)W2[k * 256 + n];
        return;
    }
    idx -= 131072;
    if (idx < 32768) {                        // Wt3[n][k] from W3[256][128]
        int n = idx / K3, k = idx % K3;
        ws[WT3_OFF + idx] = (bf16)W3[k * 128 + n];
        return;
    }
    idx -= 32768;
    if (idx < 10240) {                        // Wtc1[n][k] from Wc1[160][64]
        int n = idx / KC1, k = idx % KC1;
        ws[WTC1_OFF + idx] = (bf16)Wc1[k * 64 + n];
        return;
    }
    idx -= 10240;
    if (idx < 2048) {                         // Wtc2[n][k] from Wc2[64][32]
        int n = idx / KC2, k = idx % KC2;
        ws[WTC2_OFF + idx] = (bf16)Wc2[k * 32 + n];
        return;
    }
}

__device__ inline f32x16 z16() {
    f32x16 v;
#pragma unroll
    for (int i = 0; i < 16; ++i) v[i] = 0.0f;
    return v;
}
__device__ inline f32x4 z4() {
    f32x4 v;
#pragma unroll
    for (int i = 0; i < 4; ++i) v[i] = 0.0f;
    return v;
}

__global__ __launch_bounds__(256, 2) void fused_mlp(
    const float* __restrict__ x, const bf16* __restrict__ wt,
    const float* __restrict__ b1, const float* __restrict__ b2, const float* __restrict__ b3,
    const float* __restrict__ Ws, const float* __restrict__ bs,
    const float* __restrict__ bc1, const float* __restrict__ bc2,
    const float* __restrict__ Wc3, const float* __restrict__ bc3,
    float* __restrict__ out)
{
    __shared__ __align__(16) bf16 sXb[32 * SX];    // layer1 A; reused as H2 [32][SH2]
    __shared__ __align__(16) bf16 sH1[32 * SH1];   // layer2 A; reused as C1 [32][SC1]
    __shared__ __align__(16) bf16 sCB[32 * SCB];   // combined [seq(128) | stat(32)]
    __shared__ __align__(16) float sStat[32 * 8];
    __shared__ __align__(16) float sC2[32 * SC2];

    const int tid  = threadIdx.x;
    const int lane = tid & 63;
    const int wv   = tid >> 6;
    const int row0 = blockIdx.x * 32;

    // ---------- Phase A: load x tile, stats (fp32), Xb (bf16) ----------
    {
        const int r = tid >> 3;       // row 0..31
        const int j = tid & 7;        // 8 threads per row
        const float* xr = x + (size_t)(row0 + r) * T_DIM;
        bf16* xb = sXb + r * SX;
        float s1 = 0.f, s2 = 0.f, s3 = 0.f, s4 = 0.f;
        float mn = 3.4e38f, mx = -3.4e38f;
#pragma unroll
        for (int i = 0; i < 12; ++i) {
            int c = j + 8 * i;        // float4 chunk index, 0..91
            if (c < 91) {
                float v0 = xr[4*c+0], v1 = xr[4*c+1], v2 = xr[4*c+2], v3 = xr[4*c+3];
                s1 += v0 + v1 + v2 + v3;
                float q0 = v0*v0, q1 = v1*v1, q2 = v2*v2, q3 = v3*v3;
                s2 += q0 + q1 + q2 + q3;
                s3 += q0*v0 + q1*v1 + q2*v2 + q3*v3;
                s4 += q0*q0 + q1*q1 + q2*q2 + q3*q3;
                mn = fminf(mn, fminf(fminf(v0, v1), fminf(v2, v3)));
                mx = fmaxf(mx, fmaxf(fmaxf(v0, v1), fmaxf(v2, v3)));
                bf16x4 p = { (bf16)v0, (bf16)v1, (bf16)v2, (bf16)v3 };
                *(bf16x4*)(xb + 4 * c) = p;
            } else if (c == 91) {     // k = 364 valid; 365..367 zero pad
                float v0 = xr[364];
                float q0 = v0 * v0;
                s1 += v0; s2 += q0; s3 += q0 * v0; s4 += q0 * q0;
                mn = fminf(mn, v0); mx = fmaxf(mx, v0);
                bf16x4 p = { (bf16)v0, (bf16)0.0f, (bf16)0.0f, (bf16)0.0f };
                *(bf16x4*)(xb + 364) = p;
            }
        }
#pragma unroll
        for (int m = 1; m < 8; m <<= 1) {
            s1 += __shfl_xor(s1, m); s2 += __shfl_xor(s2, m);
            s3 += __shfl_xor(s3, m); s4 += __shfl_xor(s4, m);
            mn = fminf(mn, __shfl_xor(mn, m));
            mx = fmaxf(mx, __shfl_xor(mx, m));
        }
        if (j == 0) {
            const float Tf = (float)T_DIM;
            float mu = s1 / Tf;
            float M2 = fmaxf(s2 - s1 * mu, 0.0f);                      // sum (x-mu)^2
            float M3 = s3 - 3.f * mu * s2 + 2.f * Tf * mu * mu * mu;   // sum (x-mu)^3
            float M4 = s4 - 4.f * mu * s3 + 6.f * mu * mu * s2 - 3.f * Tf * mu * mu * mu * mu;
            float var = M2 / (Tf - 1.f);
            float sd  = sqrtf(var);
            float sk  = (M3 / Tf) / (sd * sd * sd + 1e-8f);
            float ku  = (M4 / Tf) / (var * var + 1e-8f);
            float* st = sStat + r * 8;
            st[0] = mu; st[1] = sd; st[2] = mn; st[3] = mx; st[4] = sk; st[5] = ku;
        }
    }
    __syncthreads();

    // stat features: [32 rows] x (6 -> 32), write to sCB cols 128..159 (bf16)
    {
        const int r = tid >> 3;
        const int q = tid & 7;
        const float* st = sStat + r * 8;
        float a0 = st[0], a1 = st[1], a2 = st[2], a3 = st[3], a4 = st[4], a5 = st[5];
#pragma unroll
        for (int cc = 0; cc < 4; ++cc) {
            int n = 4 * q + cc;
            float v = bs[n]
                    + a0 * Ws[0*32+n] + a1 * Ws[1*32+n] + a2 * Ws[2*32+n]
                    + a3 * Ws[3*32+n] + a4 * Ws[4*32+n] + a5 * Ws[5*32+n];
            sCB[r * SCB + 128 + n] = (bf16)v;
        }
    }

    const int l31   = lane & 31;
    const int lhalf = lane >> 5;   // 0/1

    // ---------- Layer 1: [32,368] x [368,512] -> H1 (32x32x16 MFMA) ----------
    {
        f32x16 acc[4] = { z16(), z16(), z16(), z16() };
        const bf16* ap  = sXb + l31 * SX + lhalf * 8;
        const bf16* bp0 = wt + WT1_OFF + (size_t)(128 * wv + l31) * K1 + lhalf * 8;
#pragma unroll 2
        for (int ks = 0; ks < 23; ++ks) {
            bf16x8 a = *(const bf16x8*)(ap + 16 * ks);
#pragma unroll
            for (int nt = 0; nt < 4; ++nt) {
                bf16x8 b = *(const bf16x8*)(bp0 + (size_t)nt * 32 * K1 + 16 * ks);
                acc[nt] = __builtin_amdgcn_mfma_f32_32x32x16_bf16(a, b, acc[nt], 0, 0, 0);
            }
        }
#pragma unroll
        for (int nt = 0; nt < 4; ++nt) {
            int col = 128 * wv + 32 * nt + l31;
            float bias = b1[col];
#pragma unroll
            for (int g = 0; g < 4; ++g) {
#pragma unroll
                for (int rr = 0; rr < 4; ++rr) {
                    int rowi = rr + 8 * g + 4 * lhalf;     // C/D: row=(reg&3)+8*(reg>>2)+4*(lane>>5)
                    float v = fmaxf(acc[nt][4 * g + rr] + bias, 0.0f);
                    sH1[rowi * SH1 + col] = (bf16)v;
                }
            }
        }
    }
    __syncthreads();

    // ---------- Layer 2: [32,512] x [512,256] -> H2 (in sXb region) ----------
    {
        f32x16 acc[2] = { z16(), z16() };
        const bf16* ap = sH1 + l31 * SH1 + lhalf * 8;
        const bf16* bp = wt + WT2_OFF + (size_t)(64 * wv + l31) * K2 + lhalf * 8;
#pragma unroll 2
        for (int ks = 0; ks < 32; ++ks) {
            bf16x8 a  = *(const bf16x8*)(ap + 16 * ks);
            bf16x8 c0 = *(const bf16x8*)(bp + 16 * ks);
            bf16x8 c1 = *(const bf16x8*)(bp + (size_t)32 * K2 + 16 * ks);
            acc[0] = __builtin_amdgcn_mfma_f32_32x32x16_bf16(a, c0, acc[0], 0, 0, 0);
            acc[1] = __builtin_amdgcn_mfma_f32_32x32x16_bf16(a, c1, acc[1], 0, 0, 0);
        }
        bf16* H2 = sXb;
#pragma unroll
        for (int nt = 0; nt < 2; ++nt) {
            int col = 64 * wv + 32 * nt + l31;
            float bias = b2[col];
#pragma unroll
            for (int g = 0; g < 4; ++g) {
#pragma unroll
                for (int rr = 0; rr < 4; ++rr) {
                    int rowi = rr + 8 * g + 4 * lhalf;
                    float v = fmaxf(acc[nt][4 * g + rr] + bias, 0.0f);
                    H2[rowi * SH2 + col] = (bf16)v;
                }
            }
        }
    }
    __syncthreads();

    // ---------- Layer 3: [32,256] x [256,128] -> seq (sCB cols 0..127) ----------
    {
        f32x16 acc = z16();
        const bf16* H2 = sXb;
        const bf16* ap = H2 + l31 * SH2 + lhalf * 8;
        const bf16* bp = wt + WT3_OFF + (size_t)(32 * wv + l31) * K3 + lhalf * 8;
#pragma unroll 4
        for (int ks = 0; ks < 16; ++ks) {
            bf16x8 a = *(const bf16x8*)(ap + 16 * ks);
            bf16x8 b = *(const bf16x8*)(bp + 16 * ks);
            acc = __builtin_amdgcn_mfma_f32_32x32x16_bf16(a, b, acc, 0, 0, 0);
        }
        int col = 32 * wv + l31;
        float bias = b3[col];
#pragma unroll
        for (int g = 0; g < 4; ++g) {
#pragma unroll
            for (int rr = 0; rr < 4; ++rr) {
                int rowi = rr + 8 * g + 4 * lhalf;
                float v = fmaxf(acc[4 * g + rr] + bias, 0.0f);
                sCB[rowi * SCB + col] = (bf16)v;
            }
        }
    }
    __syncthreads();

    // ---------- Layer c1: [32,160] x [160,64] -> C1 (16x16x32 MFMA) ----------
    {
        const int l15 = lane & 15;
        const int lq  = lane >> 4;              // 0..3
        const int mt  = wv & 1;
        const int ntb = (wv >> 1) * 2;          // {0,1} or {2,3}
        f32x4 acc[2] = { z4(), z4() };
        const bf16* ap = sCB + (16 * mt + l15) * SCB + lq * 8;
        const bf16* bp = wt + WTC1_OFF + (size_t)(16 * ntb + l15) * KC1 + lq * 8;
#pragma unroll
        for (int ks = 0; ks < 5; ++ks) {
            bf16x8 a  = *(const bf16x8*)(ap + 32 * ks);
            bf16x8 c0 = *(const bf16x8*)(bp + 32 * ks);
            bf16x8 c1 = *(const bf16x8*)(bp + (size_t)16 * KC1 + 32 * ks);
            acc[0] = __builtin_amdgcn_mfma_f32_16x16x32_bf16(a, c0, acc[0], 0, 0, 0);
            acc[1] = __builtin_amdgcn_mfma_f32_16x16x32_bf16(a, c1, acc[1], 0, 0, 0);
        }
        bf16* C1 = sH1;
#pragma unroll
        for (int nt = 0; nt < 2; ++nt) {
            int col = 16 * (ntb + nt) + l15;
            float bias = bc1[col];
#pragma unroll
            for (int reg = 0; reg < 4; ++reg) {
                int m = 16 * mt + lq * 4 + reg;  // C/D: row=(lane>>4)*4+reg
                float v = fmaxf(acc[nt][reg] + bias, 0.0f);
                C1[m * SC1 + col] = (bf16)v;
            }
        }
    }
    __syncthreads();

    // ---------- Layer c2: [32,64] x [64,32] -> C2 (f32 in LDS) ----------
    {
        const int l15 = lane & 15;
        const int lq  = lane >> 4;
        const int mt  = wv & 1;
        const int nt  = wv >> 1;
        f32x4 acc = z4();
        const bf16* C1 = sH1;
        const bf16* ap = C1 + (16 * mt + l15) * SC1 + lq * 8;
        const bf16* bp = wt + WTC2_OFF + (size_t)(16 * nt + l15) * KC2 + lq * 8;
#pragma unroll
        for (int ks = 0; ks < 2; ++ks) {
            bf16x8 a = *(const bf16x8*)(ap + 32 * ks);
            bf16x8 b = *(const bf16x8*)(bp + 32 * ks);
            acc = __builtin_amdgcn_mfma_f32_16x16x32_bf16(a, b, acc, 0, 0, 0);
        }
        int col = 16 * nt + l15;
        float bias = bc2[col];
#pragma unroll
        for (int reg = 0; reg < 4; ++reg) {
            int m = 16 * mt + lq * 4 + reg;
            float v = fmaxf(acc[reg] + bias, 0.0f);
            sC2[m * SC2 + col] = v;
        }
    }
    __syncthreads();

    // ---------- final: 32 -> 1 dot, sigmoid*4+6 ----------
    if (tid < 32) {
        const float* c2r = sC2 + tid * SC2;
        float z = bc3[0];
#pragma unroll
        for (int k = 0; k < 32; ++k) z += c2r[k] * Wc3[k];
        float sg = 1.0f / (1.0f + __expf(-z));
        out[row0 + tid] = sg * 4.0f + 6.0f;
    }
}

extern "C" void kernel_launch(void* const* d_in, const int* in_sizes, int n_in,
                              void* d_out, int out_size, void* d_ws, size_t ws_size,
                              hipStream_t stream) {
    const float* x   = (const float*)d_in[0];
    const float* W1  = (const float*)d_in[1];
    const float* b1  = (const float*)d_in[2];
    const float* W2  = (const float*)d_in[3];
    const float* b2  = (const float*)d_in[4];
    const float* W3  = (const float*)d_in[5];
    const float* b3  = (const float*)d_in[6];
    const float* Ws  = (const float*)d_in[7];
    const float* bs  = (const float*)d_in[8];
    const float* Wc1 = (const float*)d_in[9];
    const float* bc1 = (const float*)d_in[10];
    const float* Wc2 = (const float*)d_in[11];
    const float* bc2 = (const float*)d_in[12];
    const float* Wc3 = (const float*)d_in[13];
    const float* bc3 = (const float*)d_in[14];
    float* out = (float*)d_out;
    bf16* wt = (bf16*)d_ws;

    const int B = in_sizes[0] / T_DIM;          // 65536
    prep_weights<<<(WTOTAL + 255) / 256, 256, 0, stream>>>(W1, W2, W3, Wc1, Wc2, wt);
    fused_mlp<<<B / 32, 256, 0, stream>>>(x, wt, b1, b2, b3, Ws, bs, bc1, bc2, Wc3, bc3, out);
}

// Round 3
// 219.525 us; speedup vs baseline: 1.4188x; 1.4188x over previous
//
#include <hip/hip_runtime.h>
#include <stdint.h>
#include <stddef.h>

typedef __bf16 bf16;
typedef bf16 bf16x4 __attribute__((ext_vector_type(4)));
typedef bf16 bf16x8 __attribute__((ext_vector_type(8)));
typedef float f32x4 __attribute__((ext_vector_type(4)));
typedef float f32x16 __attribute__((ext_vector_type(16)));

#define T_DIM 365
#define K1    368     // padded K for layer 1
#define SX    376     // LDS stride (bf16) for Xb: 752B = 47*16
#define SH1   520     // 1040B = 65*16
#define K2    512
#define SH2   264     // 528B = 33*16
#define K3    256
#define SCB   184     // 368B = 23*16 (combined: 128 seq + 32 stat)
#define KC1   160
#define SC1   72      // 144B = 9*16
#define KC2   64
#define SC2   33

// ws element offsets (bf16 elements) — fragment-major packed layouts.
// Layer1: [wv(4)][nt(4)][ks(23)][lane(64)][8]   n=128wv+32nt+(l&31), k=16ks+(l>>5)*8+j
#define WT1_OFF  0
// Layer2: [wv(4)][nt(2)][ks(32)][lane][8]       n=64wv+32nt+(l&31),  k=16ks+(l>>5)*8+j
#define WT2_OFF  188416
// Layer3: [wv(4)][ks(16)][lane][8]              n=32wv+(l&31),       k=16ks+(l>>5)*8+j
#define WT3_OFF  319488
// c1: [g(2)][nt(2)][ks(5)][lane][8]             n=16*(2g+nt)+(l&15), k=32ks+(l>>4)*8+j
#define WTC1_OFF 352256
// c2: [nt(2)][ks(2)][lane][8]                   n=16nt+(l&15),       k=32ks+(l>>4)*8+j
#define WTC2_OFF 362496
#define WTOTAL   364544

__global__ void prep_weights(const float* __restrict__ W1, const float* __restrict__ W2,
                             const float* __restrict__ W3, const float* __restrict__ Wc1,
                             const float* __restrict__ Wc2, bf16* __restrict__ ws) {
    int idx = blockIdx.x * 256 + threadIdx.x;
    if (idx >= WTOTAL) return;
    if (idx < WT2_OFF) {
        int t = idx;
        int j = t & 7, lane = (t >> 3) & 63, f = t >> 9;
        int ks = f % 23; f /= 23;
        int nt = f & 3, wv = f >> 2;
        int n = 128 * wv + 32 * nt + (lane & 31);
        int k = 16 * ks + (lane >> 5) * 8 + j;
        ws[idx] = (k < T_DIM) ? (bf16)W1[k * 512 + n] : (bf16)0.0f;
    } else if (idx < WT3_OFF) {
        int t = idx - WT2_OFF;
        int j = t & 7, lane = (t >> 3) & 63, f = t >> 9;
        int ks = f & 31; f >>= 5;
        int nt = f & 1, wv = f >> 1;
        int n = 64 * wv + 32 * nt + (lane & 31);
        int k = 16 * ks + (lane >> 5) * 8 + j;
        ws[idx] = (bf16)W2[k * 256 + n];
    } else if (idx < WTC1_OFF) {
        int t = idx - WT3_OFF;
        int j = t & 7, lane = (t >> 3) & 63, f = t >> 9;
        int ks = f & 15, wv = f >> 4;
        int n = 32 * wv + (lane & 31);
        int k = 16 * ks + (lane >> 5) * 8 + j;
        ws[idx] = (bf16)W3[k * 128 + n];
    } else if (idx < WTC2_OFF) {
        int t = idx - WTC1_OFF;
        int j = t & 7, lane = (t >> 3) & 63, f = t >> 9;
        int ks = f % 5; f /= 5;
        int nt = f & 1, g = f >> 1;
        int n = 16 * (2 * g + nt) + (lane & 15);
        int k = 32 * ks + (lane >> 4) * 8 + j;
        ws[idx] = (bf16)Wc1[k * 64 + n];
    } else {
        int t = idx - WTC2_OFF;
        int j = t & 7, lane = (t >> 3) & 63, f = t >> 9;
        int ks = f & 1, nt = f >> 1;
        int n = 16 * nt + (lane & 15);
        int k = 32 * ks + (lane >> 4) * 8 + j;
        ws[idx] = (bf16)Wc2[k * 32 + n];
    }
}

__device__ inline f32x16 z16() {
    f32x16 v;
#pragma unroll
    for (int i = 0; i < 16; ++i) v[i] = 0.0f;
    return v;
}
__device__ inline f32x4 z4() {
    f32x4 v;
#pragma unroll
    for (int i = 0; i < 4; ++i) v[i] = 0.0f;
    return v;
}

__global__ __launch_bounds__(256, 2) void fused_mlp(
    const float* __restrict__ x, const bf16* __restrict__ wt,
    const float* __restrict__ b1, const float* __restrict__ b2, const float* __restrict__ b3,
    const float* __restrict__ Ws, const float* __restrict__ bs,
    const float* __restrict__ bc1, const float* __restrict__ bc2,
    const float* __restrict__ Wc3, const float* __restrict__ bc3,
    float* __restrict__ out)
{
    __shared__ __align__(16) bf16 sXb[32 * SX];    // layer1 A; reused as H2 [32][SH2]
    __shared__ __align__(16) bf16 sH1[32 * SH1];   // layer2 A; reused as C1 [32][SC1]
    __shared__ __align__(16) bf16 sCB[32 * SCB];   // combined [seq(128) | stat(32)]
    __shared__ __align__(16) float sStat[32 * 8];
    __shared__ __align__(16) float sC2[32 * SC2];

    const int tid  = threadIdx.x;
    const int lane = tid & 63;
    const int wv   = tid >> 6;
    const int row0 = blockIdx.x * 32;

    // ---------- Phase A: load x tile, stats (fp32), Xb (bf16) ----------
    {
        const int r = tid >> 3;       // row 0..31
        const int j = tid & 7;        // 8 threads per row
        const float* xr = x + (size_t)(row0 + r) * T_DIM;
        bf16* xb = sXb + r * SX;
        float s1 = 0.f, s2 = 0.f, s3 = 0.f, s4 = 0.f;
        float mn = 3.4e38f, mx = -3.4e38f;
#pragma unroll
        for (int i = 0; i < 12; ++i) {
            int c = j + 8 * i;        // float4 chunk index, 0..91
            if (c < 91) {
                float v0 = xr[4*c+0], v1 = xr[4*c+1], v2 = xr[4*c+2], v3 = xr[4*c+3];
                s1 += v0 + v1 + v2 + v3;
                float q0 = v0*v0, q1 = v1*v1, q2 = v2*v2, q3 = v3*v3;
                s2 += q0 + q1 + q2 + q3;
                s3 += q0*v0 + q1*v1 + q2*v2 + q3*v3;
                s4 += q0*q0 + q1*q1 + q2*q2 + q3*q3;
                mn = fminf(mn, fminf(fminf(v0, v1), fminf(v2, v3)));
                mx = fmaxf(mx, fmaxf(fmaxf(v0, v1), fmaxf(v2, v3)));
                bf16x4 p = { (bf16)v0, (bf16)v1, (bf16)v2, (bf16)v3 };
                *(bf16x4*)(xb + 4 * c) = p;
            } else if (c == 91) {
                float v0 = xr[364];
                float q0 = v0 * v0;
                s1 += v0; s2 += q0; s3 += q0 * v0; s4 += q0 * q0;
                mn = fminf(mn, v0); mx = fmaxf(mx, v0);
                bf16x4 p = { (bf16)v0, (bf16)0.0f, (bf16)0.0f, (bf16)0.0f };
                *(bf16x4*)(xb + 364) = p;
            }
        }
#pragma unroll
        for (int m = 1; m < 8; m <<= 1) {
            s1 += __shfl_xor(s1, m); s2 += __shfl_xor(s2, m);
            s3 += __shfl_xor(s3, m); s4 += __shfl_xor(s4, m);
            mn = fminf(mn, __shfl_xor(mn, m));
            mx = fmaxf(mx, __shfl_xor(mx, m));
        }
        if (j == 0) {
            const float Tf = (float)T_DIM;
            float mu = s1 / Tf;
            float M2 = fmaxf(s2 - s1 * mu, 0.0f);
            float M3 = s3 - 3.f * mu * s2 + 2.f * Tf * mu * mu * mu;
            float M4 = s4 - 4.f * mu * s3 + 6.f * mu * mu * s2 - 3.f * Tf * mu * mu * mu * mu;
            float var = M2 / (Tf - 1.f);
            float sd  = sqrtf(var);
            float sk  = (M3 / Tf) / (sd * sd * sd + 1e-8f);
            float ku  = (M4 / Tf) / (var * var + 1e-8f);
            float* st = sStat + r * 8;
            st[0] = mu; st[1] = sd; st[2] = mn; st[3] = mx; st[4] = sk; st[5] = ku;
        }
    }
    __syncthreads();

    // stat features: [32 rows] x (6 -> 32) into sCB cols 128..159
    {
        const int r = tid >> 3;
        const int q = tid & 7;
        const float* st = sStat + r * 8;
        float a0 = st[0], a1 = st[1], a2 = st[2], a3 = st[3], a4 = st[4], a5 = st[5];
#pragma unroll
        for (int cc = 0; cc < 4; ++cc) {
            int n = 4 * q + cc;
            float v = bs[n]
                    + a0 * Ws[0*32+n] + a1 * Ws[1*32+n] + a2 * Ws[2*32+n]
                    + a3 * Ws[3*32+n] + a4 * Ws[4*32+n] + a5 * Ws[5*32+n];
            sCB[r * SCB + 128 + n] = (bf16)v;
        }
    }

    const int l31   = lane & 31;
    const int lhalf = lane >> 5;

    // ---------- Layer 1: [32,368] x [368,512] -> H1 (32x32x16 MFMA) ----------
    {
        f32x16 acc[4] = { z16(), z16(), z16(), z16() };
        const bf16* ap = sXb + l31 * SX + lhalf * 8;
        const bf16* bp = wt + WT1_OFF + (size_t)wv * (4 * 23 * 512) + (size_t)lane * 8;
        bf16x8 pf0[4], pf1[4];
#pragma unroll
        for (int nt = 0; nt < 4; ++nt) {
            pf0[nt] = *(const bf16x8*)(bp + nt * 11776);
            pf1[nt] = *(const bf16x8*)(bp + nt * 11776 + 512);
        }
#pragma unroll
        for (int ks = 0; ks < 23; ++ks) {
            bf16x8 a = *(const bf16x8*)(ap + 16 * ks);
            bf16x8 bc[4];
#pragma unroll
            for (int nt = 0; nt < 4; ++nt) bc[nt] = (ks & 1) ? pf1[nt] : pf0[nt];
            if (ks + 2 < 23) {
#pragma unroll
                for (int nt = 0; nt < 4; ++nt) {
                    bf16x8 nb = *(const bf16x8*)(bp + nt * 11776 + (ks + 2) * 512);
                    if (ks & 1) pf1[nt] = nb; else pf0[nt] = nb;
                }
            }
#pragma unroll
            for (int nt = 0; nt < 4; ++nt)
                acc[nt] = __builtin_amdgcn_mfma_f32_32x32x16_bf16(a, bc[nt], acc[nt], 0, 0, 0);
        }
#pragma unroll
        for (int nt = 0; nt < 4; ++nt) {
            int col = 128 * wv + 32 * nt + l31;
            float bias = b1[col];
#pragma unroll
            for (int g = 0; g < 4; ++g) {
#pragma unroll
                for (int rr = 0; rr < 4; ++rr) {
                    int rowi = rr + 8 * g + 4 * lhalf;
                    float v = fmaxf(acc[nt][4 * g + rr] + bias, 0.0f);
                    sH1[rowi * SH1 + col] = (bf16)v;
                }
            }
        }
    }
    __syncthreads();

    // ---------- Layer 2: [32,512] x [512,256] -> H2 (in sXb region) ----------
    {
        f32x16 acc[2] = { z16(), z16() };
        const bf16* ap = sH1 + l31 * SH1 + lhalf * 8;
        const bf16* bp = wt + WT2_OFF + (size_t)wv * (2 * 32 * 512) + (size_t)lane * 8;
        bf16x8 pf0[2], pf1[2];
#pragma unroll
        for (int nt = 0; nt < 2; ++nt) {
            pf0[nt] = *(const bf16x8*)(bp + nt * 16384);
            pf1[nt] = *(const bf16x8*)(bp + nt * 16384 + 512);
        }
#pragma unroll
        for (int ks = 0; ks < 32; ++ks) {
            bf16x8 a = *(const bf16x8*)(ap + 16 * ks);
            bf16x8 bc[2];
#pragma unroll
            for (int nt = 0; nt < 2; ++nt) bc[nt] = (ks & 1) ? pf1[nt] : pf0[nt];
            if (ks + 2 < 32) {
#pragma unroll
                for (int nt = 0; nt < 2; ++nt) {
                    bf16x8 nb = *(const bf16x8*)(bp + nt * 16384 + (ks + 2) * 512);
                    if (ks & 1) pf1[nt] = nb; else pf0[nt] = nb;
                }
            }
            acc[0] = __builtin_amdgcn_mfma_f32_32x32x16_bf16(a, bc[0], acc[0], 0, 0, 0);
            acc[1] = __builtin_amdgcn_mfma_f32_32x32x16_bf16(a, bc[1], acc[1], 0, 0, 0);
        }
        bf16* H2 = sXb;
#pragma unroll
        for (int nt = 0; nt < 2; ++nt) {
            int col = 64 * wv + 32 * nt + l31;
            float bias = b2[col];
#pragma unroll
            for (int g = 0; g < 4; ++g) {
#pragma unroll
                for (int rr = 0; rr < 4; ++rr) {
                    int rowi = rr + 8 * g + 4 * lhalf;
                    float v = fmaxf(acc[nt][4 * g + rr] + bias, 0.0f);
                    H2[rowi * SH2 + col] = (bf16)v;
                }
            }
        }
    }
    __syncthreads();

    // ---------- Layer 3: [32,256] x [256,128] -> seq (sCB cols 0..127) ----------
    {
        f32x16 acc = z16();
        const bf16* H2 = sXb;
        const bf16* ap = H2 + l31 * SH2 + lhalf * 8;
        const bf16* bp = wt + WT3_OFF + (size_t)wv * (16 * 512) + (size_t)lane * 8;
#pragma unroll
        for (int ks = 0; ks < 16; ++ks) {
            bf16x8 a = *(const bf16x8*)(ap + 16 * ks);
            bf16x8 b = *(const bf16x8*)(bp + ks * 512);
            acc = __builtin_amdgcn_mfma_f32_32x32x16_bf16(a, b, acc, 0, 0, 0);
        }
        int col = 32 * wv + l31;
        float bias = b3[col];
#pragma unroll
        for (int g = 0; g < 4; ++g) {
#pragma unroll
            for (int rr = 0; rr < 4; ++rr) {
                int rowi = rr + 8 * g + 4 * lhalf;
                float v = fmaxf(acc[4 * g + rr] + bias, 0.0f);
                sCB[rowi * SCB + col] = (bf16)v;
            }
        }
    }
    __syncthreads();

    // ---------- Layer c1: [32,160] x [160,64] -> C1 (16x16x32 MFMA) ----------
    {
        const int l15 = lane & 15;
        const int lq  = lane >> 4;
        const int mt  = wv & 1;
        const int g   = wv >> 1;
        f32x4 acc[2] = { z4(), z4() };
        const bf16* ap = sCB + (16 * mt + l15) * SCB + lq * 8;
        const bf16* bp = wt + WTC1_OFF + (size_t)g * (2 * 5 * 512) + (size_t)lane * 8;
#pragma unroll
        for (int ks = 0; ks < 5; ++ks) {
            bf16x8 a  = *(const bf16x8*)(ap + 32 * ks);
            bf16x8 c0 = *(const bf16x8*)(bp + ks * 512);
            bf16x8 c1 = *(const bf16x8*)(bp + 5 * 512 + ks * 512);
            acc[0] = __builtin_amdgcn_mfma_f32_16x16x32_bf16(a, c0, acc[0], 0, 0, 0);
            acc[1] = __builtin_amdgcn_mfma_f32_16x16x32_bf16(a, c1, acc[1], 0, 0, 0);
        }
        bf16* C1 = sH1;
#pragma unroll
        for (int nt = 0; nt < 2; ++nt) {
            int col = 16 * (2 * g + nt) + l15;
            float bias = bc1[col];
#pragma unroll
            for (int reg = 0; reg < 4; ++reg) {
                int m = 16 * mt + lq * 4 + reg;
                float v = fmaxf(acc[nt][reg] + bias, 0.0f);
                C1[m * SC1 + col] = (bf16)v;
            }
        }
    }
    __syncthreads();

    // ---------- Layer c2: [32,64] x [64,32] -> C2 (f32 in LDS) ----------
    {
        const int l15 = lane & 15;
        const int lq  = lane >> 4;
        const int mt  = wv & 1;
        const int nt  = wv >> 1;
        f32x4 acc = z4();
        const bf16* C1 = sH1;
        const bf16* ap = C1 + (16 * mt + l15) * SC1 + lq * 8;
        const bf16* bp = wt + WTC2_OFF + (size_t)nt * (2 * 512) + (size_t)lane * 8;
#pragma unroll
        for (int ks = 0; ks < 2; ++ks) {
            bf16x8 a = *(const bf16x8*)(ap + 32 * ks);
            bf16x8 b = *(const bf16x8*)(bp + ks * 512);
            acc = __builtin_amdgcn_mfma_f32_16x16x32_bf16(a, b, acc, 0, 0, 0);
        }
        int col = 16 * nt + l15;
        float bias = bc2[col];
#pragma unroll
        for (int reg = 0; reg < 4; ++reg) {
            int m = 16 * mt + lq * 4 + reg;
            float v = fmaxf(acc[reg] + bias, 0.0f);
            sC2[m * SC2 + col] = v;
        }
    }
    __syncthreads();

    // ---------- final: 32 -> 1 dot, sigmoid*4+6 ----------
    if (tid < 32) {
        const float* c2r = sC2 + tid * SC2;
        float z = bc3[0];
#pragma unroll
        for (int k = 0; k < 32; ++k) z += c2r[k] * Wc3[k];
        float sg = 1.0f / (1.0f + __expf(-z));
        out[row0 + tid] = sg * 4.0f + 6.0f;
    }
}

extern "C" void kernel_launch(void* const* d_in, const int* in_sizes, int n_in,
                              void* d_out, int out_size, void* d_ws, size_t ws_size,
                              hipStream_t stream) {
    const float* x   = (const float*)d_in[0];
    const float* W1  = (const float*)d_in[1];
    const float* b1  = (const float*)d_in[2];
    const float* W2  = (const float*)d_in[3];
    const float* b2  = (const float*)d_in[4];
    const float* W3  = (const float*)d_in[5];
    const float* b3  = (const float*)d_in[6];
    const float* Ws  = (const float*)d_in[7];
    const float* bs  = (const float*)d_in[8];
    const float* Wc1 = (const float*)d_in[9];
    const float* bc1 = (const float*)d_in[10];
    const float* Wc2 = (const float*)d_in[11];
    const float* bc2 = (const float*)d_in[12];
    const float* Wc3 = (const float*)d_in[13];
    const float* bc3 = (const float*)d_in[14];
    float* out = (float*)d_out;
    bf16* wt = (bf16*)d_ws;

    const int B = in_sizes[0] / T_DIM;          // 65536
    prep_weights<<<(WTOTAL + 255) / 256, 256, 0, stream>>>(W1, W2, W3, Wc1, Wc2, wt);
    fused_mlp<<<B / 32, 256, 0, stream>>>(x, wt, b1, b2, b3, Ws, bs, bc1, bc2, Wc3, bc3, out);
}